// Round 14
// baseline (418.536 us; speedup 1.0000x reference)
//
#include <hip/hip_runtime.h>
#include <stdint.h>

#define N_ROWS 12288
#define GSZ (128 * 12288)  // elements per gt matrix (bf16)
#define NPART_OFF (9437184 / 4)          // float offset of node partials in ws
#define EPART_OFF ((9437184 + 6291456) / 4)

typedef __attribute__((ext_vector_type(8))) short bf16x8;
typedef __attribute__((ext_vector_type(4))) float f32x4;

union frag_u { bf16x8 v; uint32_t u[4]; };

__device__ __forceinline__ uint32_t f2bf(float x) {
  union { float f; uint32_t u; } c; c.f = x;
  return (c.u + 0x7FFFu + ((c.u >> 16) & 1u)) >> 16;
}
__device__ __forceinline__ uint32_t pk_bf(float a, float b) {
  return f2bf(a) | (f2bf(b) << 16);
}
__device__ __forceinline__ uint32_t sgn_h(float a) {
  return a > 0.f ? 0x3F80u : (a < 0.f ? 0xBF80u : 0u);
}
__device__ __forceinline__ uint32_t pk_sgn(float a, float b) {
  return sgn_h(a) | (sgn_h(b) << 16);
}

#define MFMA __builtin_amdgcn_mfma_f32_16x16x32_bf16

// ---------------------------------------------------------------------------
// Kernel 1 (R9-verified): build three bf16 TRANSPOSED matrices in gt:
//   mat0 = Gm = (feats@Wtop - feats@Wbot)/2   (pairs with S = sgn(node_adj))
//   mat1 = Gp = (feats@Wtop + feats@Wbot)/2   (pairs with A = |S|)
//   mat2 = Ge = feats@edge_w
// gt[m][n][k] = G[k][n];  pos@G1+neg@G2 == S@Gm + A@Gp.
// ---------------------------------------------------------------------------
__global__ __launch_bounds__(256) void gw_kernel(
    const float* __restrict__ feats, const float* __restrict__ node_w,
    const float* __restrict__ edge_w, uint16_t* __restrict__ gt) {
  __shared__ float lf[16 * 128];
  const int t = threadIdx.x;
  const int kb = blockIdx.x * 16;
  {
    const float4* src = (const float4*)(feats + (size_t)kb * 128);
    float4* dst = (float4*)lf;
    dst[t] = src[t];
    dst[t + 256] = src[t + 256];
  }
  __syncthreads();
  const int n = t & 127;
  const int rh = t >> 7;

  float accT[8], accB[8];
#pragma unroll
  for (int q = 0; q < 8; ++q) { accT[q] = 0.f; accB[q] = 0.f; }
  {
    const float* WT = node_w + n;
    const float* WB = node_w + 128 * 128 + n;
    for (int i = 0; i < 128; i += 2) {
      const float t0 = WT[(i + 0) * 128], t1 = WT[(i + 1) * 128];
      const float b0 = WB[(i + 0) * 128], b1 = WB[(i + 1) * 128];
#pragma unroll
      for (int q = 0; q < 8; ++q) {
        const float f0 = lf[(rh * 8 + q) * 128 + i];
        const float f1 = lf[(rh * 8 + q) * 128 + i + 1];
        accT[q] = fmaf(f1, t1, fmaf(f0, t0, accT[q]));
        accB[q] = fmaf(f1, b1, fmaf(f0, b0, accB[q]));
      }
    }
  }
  {
    uint4 o;  // Gm
    o.x = pk_bf((accT[0] - accB[0]) * 0.5f, (accT[1] - accB[1]) * 0.5f);
    o.y = pk_bf((accT[2] - accB[2]) * 0.5f, (accT[3] - accB[3]) * 0.5f);
    o.z = pk_bf((accT[4] - accB[4]) * 0.5f, (accT[5] - accB[5]) * 0.5f);
    o.w = pk_bf((accT[6] - accB[6]) * 0.5f, (accT[7] - accB[7]) * 0.5f);
    *(uint4*)(gt + (size_t)n * N_ROWS + kb + rh * 8) = o;
    uint4 p;  // Gp
    p.x = pk_bf((accT[0] + accB[0]) * 0.5f, (accT[1] + accB[1]) * 0.5f);
    p.y = pk_bf((accT[2] + accB[2]) * 0.5f, (accT[3] + accB[3]) * 0.5f);
    p.z = pk_bf((accT[4] + accB[4]) * 0.5f, (accT[5] + accB[5]) * 0.5f);
    p.w = pk_bf((accT[6] + accB[6]) * 0.5f, (accT[7] + accB[7]) * 0.5f);
    *(uint4*)(gt + GSZ + (size_t)n * N_ROWS + kb + rh * 8) = p;
  }
  {
    float accE[8];
#pragma unroll
    for (int q = 0; q < 8; ++q) accE[q] = 0.f;
    const float* WE = edge_w + n;
    for (int i = 0; i < 128; i += 2) {
      const float e0 = WE[(i + 0) * 128], e1 = WE[(i + 1) * 128];
#pragma unroll
      for (int q = 0; q < 8; ++q) {
        const float f0 = lf[(rh * 8 + q) * 128 + i];
        const float f1 = lf[(rh * 8 + q) * 128 + i + 1];
        accE[q] = fmaf(f1, e1, fmaf(f0, e0, accE[q]));
      }
    }
    uint4 o;
    o.x = pk_bf(accE[0], accE[1]);
    o.y = pk_bf(accE[2], accE[3]);
    o.z = pk_bf(accE[4], accE[5]);
    o.w = pk_bf(accE[6], accE[7]);
    *(uint4*)(gt + 2 * (size_t)GSZ + (size_t)n * N_ROWS + kb + rh * 8) = o;
  }
}

// ---------------------------------------------------------------------------
// Kernel 2: BM=256 + fold, bytes-minimal. 1536 blocks x 512 thr (8 waves),
// 2 blocks/CU (LDS 32KB x 2, VGPR ~115 <= 128 via __launch_bounds__(512,4))
// -> THREE exact residency rounds (768 node + 768 edge), zero ragged tail.
// bid<768: NODE -- stage S=sgn(adj) (one plane), A=|S| by AND in-register,
//   acc += S@Gm + A@Gp (2 B-loads/iter). else EDGE: stage bf16(adj),
//   acc += E@Ge (1 B-load/iter).
// BK=32, 16 K-slices of 768 -> 24 iters/block. slice = b&15; slice&7 == XCD
// (blockIdx round-robins XCDs) -> per-XCD gt bands 786KB, L2-resident.
// Load-bytes ledger: adj 1.21GB + B (12288/256)*9.44MB = 0.45GB + atomics
// 0.2GB = 1.9GB vs R11's 2.2 / R13's 1.8 -- with R11's latency structure.
// LDS: 2 bufs x 256 rows x 32 bf16 (64B rows), IDENTICAL node/edge layout;
// all 512 threads stage 16 floats; granule swizzle g^((r>>1)&3) (0-conflict,
// R13-verified). Per-iter = proven R11: pack+ds_write, __syncthreads,
// prefetch kt+1, B-loads + MFMA. Wave w owns cols [w*16,w*16+16): mf=16.
// ---------------------------------------------------------------------------
__global__ __launch_bounds__(512, 4) void fgc_main(
    const float* __restrict__ node_adj, const float* __restrict__ edge_adj,
    const uint16_t* __restrict__ gt, float* __restrict__ node_part,
    float* __restrict__ edge_part) {
  __shared__ __align__(128) char smem[32768];
  const int t = threadIdx.x;
  const int l = t & 63;
  const int w = t >> 6;  // 0..7: n-slice
  const bool isNode = (blockIdx.x < 768);
  const int b = isNode ? blockIdx.x : (blockIdx.x - 768);
  const int tile = b >> 4;           // 0..47: row-tiles of 256
  const int slice = b & 15;          // slice&7 == XCD id
  const int row0 = tile * 256;
  const size_t k0 = (size_t)slice * 768;

  // staging: thread t -> (row t>>1, half t&1) = 16 consecutive f32
  const int r = t >> 1, h = t & 1;
  const float* src = (isNode ? node_adj : edge_adj) +
                     (size_t)(row0 + r) * N_ROWS + k0 + h * 16;
  const int sw = (r >> 1) & 3;
  const int wOffA = r * 64 + (((h * 2) ^ sw) * 16);
  const int wOffB = r * 64 + (((h * 2 + 1) ^ sw) * 16);

  // consumer fragment addressing
  const int r15 = l & 15;
  const int gq = l >> 4;

  // B lane base: n = w*16 + r15, k = k0 + kt*32 + gq*8
  const uint16_t* gB = gt + (size_t)(w * 16 + r15) * N_ROWS + k0 + gq * 8;

  f32x4 acc[16];
#pragma unroll
  for (int a = 0; a < 16; ++a) acc[a] = {0.f, 0.f, 0.f, 0.f};

  float4 x0, x1, x2, x3;
  x0 = *(const float4*)(src);
  x1 = *(const float4*)(src + 4);
  x2 = *(const float4*)(src + 8);
  x3 = *(const float4*)(src + 12);

  if (isNode) {
    for (int kt = 0; kt < 24; ++kt) {
      char* wb2 = smem + (kt & 1) * 16384;
      {
        uint4 P;
        P.x = pk_sgn(x0.x, x0.y); P.y = pk_sgn(x0.z, x0.w);
        P.z = pk_sgn(x1.x, x1.y); P.w = pk_sgn(x1.z, x1.w);
        *(uint4*)(wb2 + wOffA) = P;
        P.x = pk_sgn(x2.x, x2.y); P.y = pk_sgn(x2.z, x2.w);
        P.z = pk_sgn(x3.x, x3.y); P.w = pk_sgn(x3.z, x3.w);
        *(uint4*)(wb2 + wOffB) = P;
      }
      __syncthreads();
      if (kt < 23) {
        const float* s2 = src + (size_t)(kt + 1) * 32;
        x0 = *(const float4*)(s2);
        x1 = *(const float4*)(s2 + 4);
        x2 = *(const float4*)(s2 + 8);
        x3 = *(const float4*)(s2 + 12);
      }
      const char* rb = smem + (kt & 1) * 16384;
      const uint16_t* gk = gB + kt * 32;
      const bf16x8 bm = *(const bf16x8*)(gk);
      const bf16x8 bp = *(const bf16x8*)(gk + GSZ);
#pragma unroll
      for (int mf = 0; mf < 16; ++mf) {
        const int rowR = mf * 16 + r15;
        const int aoff = rowR * 64 + ((gq ^ ((rowR >> 1) & 3)) * 16);
        frag_u s, a;
        s.v = *(const bf16x8*)(rb + aoff);
        a.u[0] = s.u[0] & 0x7FFF7FFFu;
        a.u[1] = s.u[1] & 0x7FFF7FFFu;
        a.u[2] = s.u[2] & 0x7FFF7FFFu;
        a.u[3] = s.u[3] & 0x7FFF7FFFu;
        acc[mf] = MFMA(s.v, bm, acc[mf], 0, 0, 0);
        acc[mf] = MFMA(a.v, bp, acc[mf], 0, 0, 0);
      }
    }
    const int col = w * 16 + r15;
#pragma unroll
    for (int mf = 0; mf < 16; ++mf) {
      const f32x4 nv = acc[mf];
#pragma unroll
      for (int q = 0; q < 4; ++q) {
        const size_t idx = (size_t)(row0 + mf * 16 + gq * 4 + q) * 128 + col;
        unsafeAtomicAdd(&node_part[idx], nv[q]);
      }
    }
  } else {
    for (int kt = 0; kt < 24; ++kt) {
      char* wb2 = smem + (kt & 1) * 16384;
      {
        uint4 E;
        E.x = pk_bf(x0.x, x0.y); E.y = pk_bf(x0.z, x0.w);
        E.z = pk_bf(x1.x, x1.y); E.w = pk_bf(x1.z, x1.w);
        *(uint4*)(wb2 + wOffA) = E;
        E.x = pk_bf(x2.x, x2.y); E.y = pk_bf(x2.z, x2.w);
        E.z = pk_bf(x3.x, x3.y); E.w = pk_bf(x3.z, x3.w);
        *(uint4*)(wb2 + wOffB) = E;
      }
      __syncthreads();
      if (kt < 23) {
        const float* s2 = src + (size_t)(kt + 1) * 32;
        x0 = *(const float4*)(s2);
        x1 = *(const float4*)(s2 + 4);
        x2 = *(const float4*)(s2 + 8);
        x3 = *(const float4*)(s2 + 12);
      }
      const char* rb = smem + (kt & 1) * 16384;
      const bf16x8 be = *(const bf16x8*)(gB + kt * 32 + 2 * (size_t)GSZ);
#pragma unroll
      for (int mf = 0; mf < 16; ++mf) {
        const int rowR = mf * 16 + r15;
        const int aoff = rowR * 64 + ((gq ^ ((rowR >> 1) & 3)) * 16);
        const bf16x8 ae = *(const bf16x8*)(rb + aoff);
        acc[mf] = MFMA(ae, be, acc[mf], 0, 0, 0);
      }
    }
    const int col = w * 16 + r15;
#pragma unroll
    for (int mf = 0; mf < 16; ++mf) {
      const f32x4 ev = acc[mf];
#pragma unroll
      for (int q = 0; q < 4; ++q) {
        const size_t idx = (size_t)(row0 + mf * 16 + gq * 4 + q) * 128 + col;
        unsafeAtomicAdd(&edge_part[idx], ev[q]);
      }
    }
  }
}

// ---------------------------------------------------------------------------
// Kernel 3: out = relu(node_part + node_bias) + edge_part + edge_bias
// ---------------------------------------------------------------------------
__global__ __launch_bounds__(256) void fgc_final(
    const float* __restrict__ node_part, const float* __restrict__ edge_part,
    const float* __restrict__ node_bias, const float* __restrict__ edge_bias,
    float* __restrict__ out) {
  const int idx = blockIdx.x * 256 + threadIdx.x;  // one float4 each
  const int col = (idx * 4) & 127;
  const float4 n = ((const float4*)node_part)[idx];
  const float4 e = ((const float4*)edge_part)[idx];
  const float4 nb = *(const float4*)(node_bias + col);
  const float4 eb = *(const float4*)(edge_bias + col);
  float4 o;
  o.x = fmaxf(n.x + nb.x, 0.f) + e.x + eb.x;
  o.y = fmaxf(n.y + nb.y, 0.f) + e.y + eb.y;
  o.z = fmaxf(n.z + nb.z, 0.f) + e.z + eb.z;
  o.w = fmaxf(n.w + nb.w, 0.f) + e.w + eb.w;
  ((float4*)out)[idx] = o;
}

extern "C" void kernel_launch(void* const* d_in, const int* in_sizes, int n_in,
                              void* d_out, int out_size, void* d_ws, size_t ws_size,
                              hipStream_t stream) {
  const float* feats = (const float*)d_in[0];
  const float* node_adj = (const float*)d_in[1];
  const float* edge_adj = (const float*)d_in[2];
  const float* node_w = (const float*)d_in[3];
  const float* node_b = (const float*)d_in[4];
  const float* edge_w = (const float*)d_in[5];
  const float* edge_b = (const float*)d_in[6];
  uint16_t* gt = (uint16_t*)d_ws;                 // 9.44 MB
  float* node_part = (float*)d_ws + NPART_OFF;    // 6.29 MB
  float* edge_part = (float*)d_ws + EPART_OFF;    // 6.29 MB

  gw_kernel<<<768, 256, 0, stream>>>(feats, node_w, edge_w, gt);
  hipMemsetAsync((char*)d_ws + 9437184, 0, 2 * 6291456, stream);
  fgc_main<<<1536, 512, 0, stream>>>(node_adj, edge_adj, gt,
                                     node_part, edge_part);
  fgc_final<<<1536, 256, 0, stream>>>(node_part, edge_part, node_b, edge_b,
                                      (float*)d_out);
}

// Round 15
// 353.031 us; speedup vs baseline: 1.1855x; 1.1855x over previous
//
#include <hip/hip_runtime.h>
#include <stdint.h>

#define N_ROWS 12288
#define GSZ (128 * 12288)  // elements per G matrix (bf16)
#define NPART_OFF (9437184 / 4)          // float offset of node partials in ws
#define EPART_OFF ((9437184 + 6291456) / 4)

typedef __attribute__((ext_vector_type(8))) short bf16x8;
typedef __attribute__((ext_vector_type(4))) float f32x4;

__device__ __forceinline__ uint32_t f2bf(float x) {
  union { float f; uint32_t u; } c; c.f = x;
  return (c.u + 0x7FFFu + ((c.u >> 16) & 1u)) >> 16;
}
__device__ __forceinline__ uint32_t pk_bf(float a, float b) {
  return f2bf(a) | (f2bf(b) << 16);
}
__device__ __forceinline__ uint32_t pk_pos(float a, float b) {
  return (a > 0.f ? 0x3F80u : 0u) | (b > 0.f ? 0x3F800000u : 0u);
}
__device__ __forceinline__ uint32_t pk_neg(float a, float b) {
  return (a < 0.f ? 0x3F80u : 0u) | (b < 0.f ? 0x3F800000u : 0u);
}

#define MFMA __builtin_amdgcn_mfma_f32_16x16x32_bf16

// ---------------------------------------------------------------------------
// Kernel 1: G_j = feats @ W_j  (fp32), stored bf16 TRANSPOSED:
//   gt[j][n][k] = (feats @ W_j)[k][n]
// ---------------------------------------------------------------------------
__global__ __launch_bounds__(256) void gw_kernel(
    const float* __restrict__ feats, const float* __restrict__ node_w,
    const float* __restrict__ edge_w, uint16_t* __restrict__ gt) {
  __shared__ float lf[16 * 128];
  const int t = threadIdx.x;
  const int kb = blockIdx.x * 16;
  {
    const float4* src = (const float4*)(feats + (size_t)kb * 128);
    float4* dst = (float4*)lf;
    dst[t] = src[t];
    dst[t + 256] = src[t + 256];
  }
  __syncthreads();
  const int n = t & 127;
  const int rh = t >> 7;
  const float* wb[3] = {node_w, node_w + 128 * 128, edge_w};
#pragma unroll
  for (int j = 0; j < 3; ++j) {
    const float* W = wb[j] + n;
    float acc[8];
#pragma unroll
    for (int q = 0; q < 8; ++q) acc[q] = 0.f;
    for (int i = 0; i < 128; i += 4) {
      const float w0 = W[(i + 0) * 128];
      const float w1 = W[(i + 1) * 128];
      const float w2 = W[(i + 2) * 128];
      const float w3 = W[(i + 3) * 128];
#pragma unroll
      for (int q = 0; q < 8; ++q) {
        const float4 f = *(const float4*)&lf[(rh * 8 + q) * 128 + i];
        acc[q] = fmaf(f.w, w3, fmaf(f.z, w2, fmaf(f.y, w1, fmaf(f.x, w0, acc[q]))));
      }
    }
    uint4 o;
    o.x = pk_bf(acc[0], acc[1]);
    o.y = pk_bf(acc[2], acc[3]);
    o.z = pk_bf(acc[4], acc[5]);
    o.w = pk_bf(acc[6], acc[7]);
    *(uint4*)(gt + (size_t)j * GSZ + (size_t)n * N_ROWS + kb + rh * 8) = o;
  }
}

// ---------------------------------------------------------------------------
// Kernel 2 (R11 best): split node/edge block types to halve B (gt) traffic.
// 1536 blocks x 512 thr (8 waves). bid<768: NODE (pos+neg planes, 2 B-loads,
// accn[8]); bid>=768: EDGE (1 plane, 1 B-load, acce[8]). BM=128, BK=32,
// 8 K-slices of 1536 (48 iters), slice = b&7 = XCD (gt slice L2-resident).
// Each wave owns 16 cols (nf=1, mf=8). LDS: 2 bufs x 2 planes x 128 x 32
// bf16 = 32KB max; granule swizzle g ^ ((row>>1)&3) (free 2-way).
// Per-iter: pack+ds_write, __syncthreads, prefetch, B-loads + MFMA.
// ---------------------------------------------------------------------------
__global__ __launch_bounds__(512, 4) void fgc_main(
    const float* __restrict__ node_adj, const float* __restrict__ edge_adj,
    const uint16_t* __restrict__ gt, float* __restrict__ node_part,
    float* __restrict__ edge_part) {
  __shared__ __align__(128) char smem[32768];
  const int t = threadIdx.x;
  const int l = t & 63;
  const int w = t >> 6;  // 0..7: n-slice
  const bool isNode = (blockIdx.x < 768);
  const int b = isNode ? blockIdx.x : blockIdx.x - 768;
  const int slice = b & 7;
  const int row0 = (b >> 3) * 128;   // 96 row-tiles
  const size_t k0 = (size_t)slice * 1536;

  // staging: thread t owns (row t>>2, granule t&3) = 8 consecutive f32
  const int r = t >> 2, o = t & 3;
  const float* src = (isNode ? node_adj : edge_adj) +
                     (size_t)(row0 + r) * N_ROWS + k0 + o * 8;
  const int wOff = r * 64 + ((o ^ ((r >> 1) & 3)) * 16);

  // A-frag read: row = mf*16 + r15, granule gq, swizzle (row>>1)&3
  const int r15 = l & 15;
  const int gq = l >> 4;

  // B lane base: n = w*16 + r15, k = k0 + kt*32 + gq*8
  const uint16_t* gB = gt + (size_t)(w * 16 + r15) * N_ROWS + k0 + gq * 8;

  f32x4 acc[8];
#pragma unroll
  for (int a = 0; a < 8; ++a) acc[a] = {0.f, 0.f, 0.f, 0.f};

  float4 rn0, rn1;
  rn0 = *(const float4*)(src);
  rn1 = *(const float4*)(src + 4);

  if (isNode) {
    for (int kt = 0; kt < 48; ++kt) {
      char* wb2 = smem + (kt & 1) * 16384;
      {
        uint4 P, Q;
        P.x = pk_pos(rn0.x, rn0.y); P.y = pk_pos(rn0.z, rn0.w);
        P.z = pk_pos(rn1.x, rn1.y); P.w = pk_pos(rn1.z, rn1.w);
        Q.x = pk_neg(rn0.x, rn0.y); Q.y = pk_neg(rn0.z, rn0.w);
        Q.z = pk_neg(rn1.x, rn1.y); Q.w = pk_neg(rn1.z, rn1.w);
        *(uint4*)(wb2 + wOff) = P;
        *(uint4*)(wb2 + 8192 + wOff) = Q;
      }
      __syncthreads();
      if (kt < 47) {
        const size_t ko = (size_t)(kt + 1) * 32;
        rn0 = *(const float4*)(src + ko);
        rn1 = *(const float4*)(src + ko + 4);
      }
      const char* rb = smem + (kt & 1) * 16384;
      const uint16_t* gk = gB + kt * 32;
      const bf16x8 b1 = *(const bf16x8*)(gk);
      const bf16x8 b2 = *(const bf16x8*)(gk + GSZ);
#pragma unroll
      for (int mf = 0; mf < 8; ++mf) {
        const int rowR = mf * 16 + r15;
        const int aoff = rowR * 64 + ((gq ^ ((rowR >> 1) & 3)) * 16);
        const bf16x8 ap = *(const bf16x8*)(rb + aoff);
        const bf16x8 an = *(const bf16x8*)(rb + 8192 + aoff);
        acc[mf] = MFMA(ap, b1, acc[mf], 0, 0, 0);
        acc[mf] = MFMA(an, b2, acc[mf], 0, 0, 0);
      }
    }
    const int col = w * 16 + r15;
#pragma unroll
    for (int mf = 0; mf < 8; ++mf) {
      const f32x4 nv = acc[mf];
#pragma unroll
      for (int q = 0; q < 4; ++q) {
        const size_t idx = (size_t)(row0 + mf * 16 + gq * 4 + q) * 128 + col;
        unsafeAtomicAdd(&node_part[idx], nv[q]);
      }
    }
  } else {
    for (int kt = 0; kt < 48; ++kt) {
      char* wb2 = smem + (kt & 1) * 16384;
      {
        uint4 E;
        E.x = pk_bf(rn0.x, rn0.y); E.y = pk_bf(rn0.z, rn0.w);
        E.z = pk_bf(rn1.x, rn1.y); E.w = pk_bf(rn1.z, rn1.w);
        *(uint4*)(wb2 + wOff) = E;
      }
      __syncthreads();
      if (kt < 47) {
        const size_t ko = (size_t)(kt + 1) * 32;
        rn0 = *(const float4*)(src + ko);
        rn1 = *(const float4*)(src + ko + 4);
      }
      const char* rb = smem + (kt & 1) * 16384;
      const bf16x8 b3 = *(const bf16x8*)(gB + kt * 32 + 2 * (size_t)GSZ);
#pragma unroll
      for (int mf = 0; mf < 8; ++mf) {
        const int rowR = mf * 16 + r15;
        const int aoff = rowR * 64 + ((gq ^ ((rowR >> 1) & 3)) * 16);
        const bf16x8 ae = *(const bf16x8*)(rb + aoff);
        acc[mf] = MFMA(ae, b3, acc[mf], 0, 0, 0);
      }
    }
    const int col = w * 16 + r15;
#pragma unroll
    for (int mf = 0; mf < 8; ++mf) {
      const f32x4 ev = acc[mf];
#pragma unroll
      for (int q = 0; q < 4; ++q) {
        const size_t idx = (size_t)(row0 + mf * 16 + gq * 4 + q) * 128 + col;
        unsafeAtomicAdd(&edge_part[idx], ev[q]);
      }
    }
  }
}

// ---------------------------------------------------------------------------
// Kernel 3: out = relu(node_part + node_bias) + edge_part + edge_bias
// ---------------------------------------------------------------------------
__global__ __launch_bounds__(256) void fgc_final(
    const float* __restrict__ node_part, const float* __restrict__ edge_part,
    const float* __restrict__ node_bias, const float* __restrict__ edge_bias,
    float* __restrict__ out) {
  const int idx = blockIdx.x * 256 + threadIdx.x;  // one float4 each
  const int col = (idx * 4) & 127;
  const float4 n = ((const float4*)node_part)[idx];
  const float4 e = ((const float4*)edge_part)[idx];
  const float4 nb = *(const float4*)(node_bias + col);
  const float4 eb = *(const float4*)(edge_bias + col);
  float4 o;
  o.x = fmaxf(n.x + nb.x, 0.f) + e.x + eb.x;
  o.y = fmaxf(n.y + nb.y, 0.f) + e.y + eb.y;
  o.z = fmaxf(n.z + nb.z, 0.f) + e.z + eb.z;
  o.w = fmaxf(n.w + nb.w, 0.f) + e.w + eb.w;
  ((float4*)out)[idx] = o;
}

extern "C" void kernel_launch(void* const* d_in, const int* in_sizes, int n_in,
                              void* d_out, int out_size, void* d_ws, size_t ws_size,
                              hipStream_t stream) {
  const float* feats = (const float*)d_in[0];
  const float* node_adj = (const float*)d_in[1];
  const float* edge_adj = (const float*)d_in[2];
  const float* node_w = (const float*)d_in[3];
  const float* node_b = (const float*)d_in[4];
  const float* edge_w = (const float*)d_in[5];
  const float* edge_b = (const float*)d_in[6];
  uint16_t* gt = (uint16_t*)d_ws;                 // 9.44 MB
  float* node_part = (float*)d_ws + NPART_OFF;    // 6.29 MB
  float* edge_part = (float*)d_ws + EPART_OFF;    // 6.29 MB

  gw_kernel<<<768, 256, 0, stream>>>(feats, node_w, edge_w, gt);
  hipMemsetAsync((char*)d_ws + 9437184, 0, 2 * 6291456, stream);
  fgc_main<<<1536, 512, 0, stream>>>(node_adj, edge_adj, gt,
                                     node_part, edge_part);
  fgc_final<<<1536, 256, 0, stream>>>(node_part, edge_part, node_b, edge_b,
                                      (float*)d_out);
}